// Round 1
// baseline (544.359 us; speedup 1.0000x reference)
//
#include <hip/hip_runtime.h>
#include <math.h>

#define BATCH  8192
#define D_IN   592
#define FBANKS 8
#define P1     147   // pool1 output length
#define P2     36    // pool2 output length
#define NW     4     // waves (rows) per block

__global__ __launch_bounds__(256) void fb_kernel(
    const float* __restrict__ x,
    const float* __restrict__ c1w, const float* __restrict__ c1b,
    const float* __restrict__ c2w, const float* __restrict__ c2b,
    const float* __restrict__ l1w, const float* __restrict__ l1b,
    const float* __restrict__ l2w, const float* __restrict__ l2b,
    const float* __restrict__ l3w, const float* __restrict__ l3b,
    float* __restrict__ outH, float* __restrict__ outXF,
    float* __restrict__ outXS, float* __restrict__ outF0)
{
    // ---- weights staged once per block ----
    __shared__ float s_c1w[72];    // (8,3,1,3)
    __shared__ float s_c1b[24];    // (8,3)
    __shared__ float s_c2w[72];    // (8,1,3,3)
    __shared__ float s_c2b[8];     // (8,1)
    __shared__ float s_l1w[5760];  // (8,20,36)
    __shared__ float s_l1b[160];   // (8,20)
    __shared__ float s_l2w[1600];  // (8,10,20)
    __shared__ float s_l2b[80];    // (8,10)
    __shared__ float s_l3w[80];    // (8,1,10)
    __shared__ float s_l3b[8];     // (8,1)
    // ---- per-wave scratch ----
    __shared__ float s_xa[NW][D_IN];
    __shared__ float s_p1[NW][3][P1 + 1];  // +1 pad
    __shared__ float s_p2[NW][P2];
    __shared__ float s_l1o[NW][20];
    __shared__ float s_l2o[NW][12];
    __shared__ float s_f0[NW];

    const int tid  = threadIdx.x;
    const int wave = tid >> 6;
    const int lane = tid & 63;
    const int row  = blockIdx.x * NW + wave;

    for (int i = tid; i < 72;   i += 256) s_c1w[i] = c1w[i];
    for (int i = tid; i < 24;   i += 256) s_c1b[i] = c1b[i];
    for (int i = tid; i < 72;   i += 256) s_c2w[i] = c2w[i];
    for (int i = tid; i < 8;    i += 256) s_c2b[i] = c2b[i];
    for (int i = tid; i < 5760; i += 256) s_l1w[i] = l1w[i];
    for (int i = tid; i < 160;  i += 256) s_l1b[i] = l1b[i];
    for (int i = tid; i < 1600; i += 256) s_l2w[i] = l2w[i];
    for (int i = tid; i < 80;   i += 256) s_l2b[i] = l2b[i];
    for (int i = tid; i < 80;   i += 256) s_l3w[i] = l3w[i];
    for (int i = tid; i < 8;    i += 256) s_l3b[i] = l3b[i];

    float* xa = s_xa[wave];
    for (int d = lane; d < D_IN; d += 64)
        xa[d] = x[(size_t)row * D_IN + d];
    __syncthreads();

    const float inv2w2 = 1.0f / (2.0f * 5.0f * 5.0f);

    for (int bank = 0; bank < FBANKS; ++bank) {
        // conv weights -> registers (wave-uniform LDS broadcast reads)
        float w1[3][3], b1[3], w2[3][3];
        #pragma unroll
        for (int c = 0; c < 3; ++c) {
            b1[c] = s_c1b[bank * 3 + c];
            #pragma unroll
            for (int k = 0; k < 3; ++k) {
                w1[c][k] = s_c1w[bank * 9 + c * 3 + k];
                w2[c][k] = s_c2w[bank * 9 + c * 3 + k];
            }
        }
        const float b2 = s_c2b[bank];

        // ---- conv1 (k=3,s=2) + maxpool(3,2) + relu, fused ----
        // pooled pos p covers x[4p .. 4p+6]
        for (int p = lane; p < P1; p += 64) {
            float xv[7];
            #pragma unroll
            for (int t = 0; t < 7; ++t) xv[t] = xa[4 * p + t];
            #pragma unroll
            for (int c = 0; c < 3; ++c) {
                float v0 = w1[c][0] * xv[0] + w1[c][1] * xv[1] + w1[c][2] * xv[2];
                float v1 = w1[c][0] * xv[2] + w1[c][1] * xv[3] + w1[c][2] * xv[4];
                float v2 = w1[c][0] * xv[4] + w1[c][1] * xv[5] + w1[c][2] * xv[6];
                float m  = fmaxf(fmaxf(v0, v1), v2) + b1[c];
                s_p1[wave][c][p] = fmaxf(m, 0.0f);
            }
        }
        __syncthreads();

        // ---- conv2 (3ch->1, k=3,s=2) + maxpool(3,2) + relu, fused ----
        // pooled pos q covers p1[c][4q .. 4q+6]
        if (lane < P2) {
            const int q = lane;
            float vm[3];
            #pragma unroll
            for (int m = 0; m < 3; ++m) {
                float s = b2;
                #pragma unroll
                for (int c = 0; c < 3; ++c)
                    #pragma unroll
                    for (int k = 0; k < 3; ++k)
                        s += w2[c][k] * s_p1[wave][c][4 * q + 2 * m + k];
                vm[m] = s;
            }
            float mm = fmaxf(fmaxf(vm[0], vm[1]), vm[2]);
            s_p2[wave][q] = fmaxf(mm, 0.0f);
        }
        __syncthreads();

        // ---- lin1: 36 -> 20, relu ----
        if (lane < 20) {
            float acc = s_l1b[bank * 20 + lane];
            const float* wr = &s_l1w[bank * 720 + lane * 36];
            #pragma unroll
            for (int k = 0; k < 36; ++k) acc += wr[k] * s_p2[wave][k];
            s_l1o[wave][lane] = fmaxf(acc, 0.0f);
        }
        __syncthreads();

        // ---- lin2: 20 -> 10, relu ----
        if (lane < 10) {
            float acc = s_l2b[bank * 10 + lane];
            const float* wr = &s_l2w[bank * 200 + lane * 20];
            #pragma unroll
            for (int k = 0; k < 20; ++k) acc += wr[k] * s_l1o[wave][k];
            s_l2o[wave][lane] = fmaxf(acc, 0.0f);
        }
        __syncthreads();

        // ---- lin3: 10 -> 1, sigmoid, f0 = D * sig ----
        if (lane == 0) {
            float acc = s_l3b[bank];
            #pragma unroll
            for (int k = 0; k < 10; ++k)
                acc += s_l3w[bank * 10 + k] * s_l2o[wave][k];
            float sig = 1.0f / (1.0f + __expf(-acc));
            float f0  = (float)D_IN * sig;
            s_f0[wave] = f0;
            outF0[(size_t)bank * BATCH + row] = f0;
        }
        __syncthreads();

        // ---- Gaussian filter + outputs + state update ----
        const float f0 = s_f0[wave];
        const size_t base = ((size_t)bank * BATCH + row) * D_IN;
        for (int d = lane; d < D_IN; d += 64) {
            float xv = xa[d];
            float df = (float)d - f0;
            float Hv = __expf(-df * df * inv2w2);
            float xf = xv * Hv;
            outXS[base + d] = xv;
            outH[base + d]  = Hv;
            outXF[base + d] = xf;
            xa[d] = xv - xf;
        }
        __syncthreads();
    }
}

extern "C" void kernel_launch(void* const* d_in, const int* in_sizes, int n_in,
                              void* d_out, int out_size, void* d_ws, size_t ws_size,
                              hipStream_t stream) {
    const float* x   = (const float*)d_in[0];
    const float* c1w = (const float*)d_in[1];
    const float* c1b = (const float*)d_in[2];
    const float* c2w = (const float*)d_in[3];
    const float* c2b = (const float*)d_in[4];
    const float* l1w = (const float*)d_in[5];
    const float* l1b = (const float*)d_in[6];
    const float* l2w = (const float*)d_in[7];
    const float* l2b = (const float*)d_in[8];
    const float* l3w = (const float*)d_in[9];
    const float* l3b = (const float*)d_in[10];

    float* out = (float*)d_out;
    const size_t plane = (size_t)FBANKS * BATCH * D_IN;  // 38,797,312
    float* outH  = out;
    float* outXF = out + plane;
    float* outXS = out + 2 * plane;
    float* outF0 = out + 3 * plane;

    dim3 grid(BATCH / NW);
    dim3 block(256);
    fb_kernel<<<grid, block, 0, stream>>>(x, c1w, c1b, c2w, c2b,
                                          l1w, l1b, l2w, l2b, l3w, l3b,
                                          outH, outXF, outXS, outF0);
}

// Round 2
// 499.034 us; speedup vs baseline: 1.0908x; 1.0908x over previous
//
#include <hip/hip_runtime.h>
#include <math.h>

#define BATCH  8192
#define D_IN   592
#define FBANKS 8
#define P1     147   // pool1 output length
#define P2     36    // pool2 output length
#define P1PAD  152   // padded row (16B-multiple stride, room for b128 over-read)
#define NW     4     // waves (rows) per block

// Wave-synchronous ordering: CDNA waves are lockstep (one PC + exec mask) and
// DS ops complete in program order per wave, so producer->consumer through
// per-wave LDS scratch needs only a compiler reordering fence, not s_barrier.
#define WAVE_SYNC() do { __builtin_amdgcn_wave_barrier(); asm volatile("" ::: "memory"); } while (0)

__global__ __launch_bounds__(256) void fb_kernel(
    const float* __restrict__ x,
    const float* __restrict__ c1w, const float* __restrict__ c1b,
    const float* __restrict__ c2w, const float* __restrict__ c2b,
    const float* __restrict__ l1w, const float* __restrict__ l1b,
    const float* __restrict__ l2w, const float* __restrict__ l2b,
    const float* __restrict__ l3w, const float* __restrict__ l3b,
    float* __restrict__ outH, float* __restrict__ outXF,
    float* __restrict__ outXS, float* __restrict__ outF0)
{
    // ---- block-shared weights (lin1_w deliberately NOT staged: 23KB LDS
    //      would cut occupancy 6->3 blocks/CU; it L1-caches at 23KB total) ----
    __shared__ __align__(16) float s_c1w[72];    // (8,3,1,3)
    __shared__ __align__(16) float s_c1b[24];    // (8,3)
    __shared__ __align__(16) float s_c2w[72];    // (8,1,3,3)
    __shared__ __align__(16) float s_c2b[8];     // (8,1)
    __shared__ __align__(16) float s_l1b[160];   // (8,20)
    __shared__ __align__(16) float s_l2w[1600];  // (8,10,20)
    __shared__ __align__(16) float s_l2b[80];    // (8,10)
    __shared__ __align__(16) float s_l3w[80];    // (8,1,10)
    __shared__ __align__(16) float s_l3b[8];     // (8,1)
    // ---- per-wave scratch (no cross-wave sharing -> no __syncthreads) ----
    __shared__ __align__(16) float s_xa[NW][D_IN];
    __shared__ __align__(16) float s_p1[NW][3][P1PAD];
    __shared__ __align__(16) float s_p2[NW][40];
    __shared__ __align__(16) float s_l1o[NW][20];
    __shared__ __align__(16) float s_l2o[NW][12];

    const int tid  = threadIdx.x;
    const int wave = tid >> 6;
    const int lane = tid & 63;
    const int row  = blockIdx.x * NW + wave;

    for (int i = tid; i < 72;   i += 256) s_c1w[i] = c1w[i];
    for (int i = tid; i < 24;   i += 256) s_c1b[i] = c1b[i];
    for (int i = tid; i < 72;   i += 256) s_c2w[i] = c2w[i];
    for (int i = tid; i < 8;    i += 256) s_c2b[i] = c2b[i];
    for (int i = tid; i < 160;  i += 256) s_l1b[i] = l1b[i];
    for (int i = tid; i < 1600; i += 256) s_l2w[i] = l2w[i];
    for (int i = tid; i < 80;   i += 256) s_l2b[i] = l2b[i];
    for (int i = tid; i < 80;   i += 256) s_l3w[i] = l3w[i];
    for (int i = tid; i < 8;    i += 256) s_l3b[i] = l3b[i];

    float* xa = s_xa[wave];
    {
        const float* xrow = x + (size_t)row * D_IN;
        for (int i = lane; i < 148; i += 64) {           // 148 float4 = 592 floats
            float4 v = *(const float4*)&xrow[4 * i];
            *(float4*)&xa[4 * i] = v;
        }
    }
    __syncthreads();   // the ONLY block barrier: weights ready

    const float inv2w2 = 1.0f / (2.0f * 5.0f * 5.0f);

    for (int bank = 0; bank < FBANKS; ++bank) {
        float w1[3][3], b1[3], w2[3][3];
        #pragma unroll
        for (int c = 0; c < 3; ++c) {
            b1[c] = s_c1b[bank * 3 + c];
            #pragma unroll
            for (int k = 0; k < 3; ++k) {
                w1[c][k] = s_c1w[bank * 9 + c * 3 + k];
                w2[c][k] = s_c2w[bank * 9 + c * 3 + k];
            }
        }
        const float b2 = s_c2b[bank];

        // ---- conv1(k3,s2)+maxpool(3,2)+relu: pooled p covers x[4p..4p+6] ----
        for (int p = lane; p < P1; p += 64) {
            float4 a = *(const float4*)&xa[4 * p];       // 4p..4p+3
            float4 b = *(const float4*)&xa[4 * p + 4];   // 4p+4..4p+7 (max 591)
            float xv0 = a.x, xv1 = a.y, xv2 = a.z, xv3 = a.w;
            float xv4 = b.x, xv5 = b.y, xv6 = b.z;
            #pragma unroll
            for (int c = 0; c < 3; ++c) {
                float v0 = w1[c][0] * xv0 + w1[c][1] * xv1 + w1[c][2] * xv2;
                float v1 = w1[c][0] * xv2 + w1[c][1] * xv3 + w1[c][2] * xv4;
                float v2 = w1[c][0] * xv4 + w1[c][1] * xv5 + w1[c][2] * xv6;
                float m  = fmaxf(fmaxf(v0, v1), v2) + b1[c];
                s_p1[wave][c][p] = fmaxf(m, 0.0f);
            }
        }
        WAVE_SYNC();

        // ---- conv2(3ch->1,k3,s2)+maxpool(3,2)+relu: q covers p1[c][4q..4q+6] ----
        if (lane < P2) {
            const int q = lane;
            float acc0 = b2, acc1 = b2, acc2 = b2;
            #pragma unroll
            for (int c = 0; c < 3; ++c) {
                const float* r = s_p1[wave][c];
                float4 a = *(const float4*)&r[4 * q];
                float4 b = *(const float4*)&r[4 * q + 4];
                float v0 = a.x, v1 = a.y, v2 = a.z, v3 = a.w, v4 = b.x, v5 = b.y, v6 = b.z;
                acc0 += w2[c][0] * v0 + w2[c][1] * v1 + w2[c][2] * v2;
                acc1 += w2[c][0] * v2 + w2[c][1] * v3 + w2[c][2] * v4;
                acc2 += w2[c][0] * v4 + w2[c][1] * v5 + w2[c][2] * v6;
            }
            float mm = fmaxf(fmaxf(acc0, acc1), acc2);
            s_p2[wave][q] = fmaxf(mm, 0.0f);
        }
        WAVE_SYNC();

        // ---- lin1: 36 -> 20, relu (weights straight from global: L1-resident) ----
        if (lane < 20) {
            const float4* wr = (const float4*)(l1w + bank * 720 + lane * 36);
            float acc = s_l1b[bank * 20 + lane];
            #pragma unroll
            for (int k = 0; k < 9; ++k) {
                float4 w = wr[k];
                float4 v = *(const float4*)&s_p2[wave][4 * k];
                acc += w.x * v.x + w.y * v.y + w.z * v.z + w.w * v.w;
            }
            s_l1o[wave][lane] = fmaxf(acc, 0.0f);
        }
        WAVE_SYNC();

        // ---- lin2: 20 -> 10, relu ----
        if (lane < 10) {
            const float4* wr = (const float4*)&s_l2w[bank * 200 + lane * 20];
            float acc = s_l2b[bank * 10 + lane];
            #pragma unroll
            for (int k = 0; k < 5; ++k) {
                float4 w = wr[k];
                float4 v = *(const float4*)&s_l1o[wave][4 * k];
                acc += w.x * v.x + w.y * v.y + w.z * v.z + w.w * v.w;
            }
            s_l2o[wave][lane] = fmaxf(acc, 0.0f);
        }
        WAVE_SYNC();

        // ---- lin3: 10 -> 1, sigmoid, f0 = D*sig; broadcast via shfl ----
        float f0v = 0.0f;
        if (lane == 0) {
            float acc = s_l3b[bank];
            #pragma unroll
            for (int k = 0; k < 10; ++k)
                acc += s_l3w[bank * 10 + k] * s_l2o[wave][k];
            float sig = 1.0f / (1.0f + __expf(-acc));
            f0v = (float)D_IN * sig;
            outF0[(size_t)bank * BATCH + row] = f0v;
        }
        f0v = __shfl(f0v, 0);

        // ---- Gaussian filter + vectorized outputs + state update ----
        const size_t base = ((size_t)bank * BATCH + row) * D_IN;
        for (int i = lane; i < 148; i += 64) {
            float4 xv = *(const float4*)&xa[4 * i];
            float d0 = (float)(4 * i)     - f0v;
            float d1 = (float)(4 * i + 1) - f0v;
            float d2 = (float)(4 * i + 2) - f0v;
            float d3 = (float)(4 * i + 3) - f0v;
            float4 Hv, xf, xn;
            Hv.x = __expf(-d0 * d0 * inv2w2);
            Hv.y = __expf(-d1 * d1 * inv2w2);
            Hv.z = __expf(-d2 * d2 * inv2w2);
            Hv.w = __expf(-d3 * d3 * inv2w2);
            xf.x = xv.x * Hv.x;  xf.y = xv.y * Hv.y;
            xf.z = xv.z * Hv.z;  xf.w = xv.w * Hv.w;
            xn.x = xv.x - xf.x;  xn.y = xv.y - xf.y;
            xn.z = xv.z - xf.z;  xn.w = xv.w - xf.w;
            *(float4*)&outXS[base + 4 * i] = xv;
            *(float4*)&outH [base + 4 * i] = Hv;
            *(float4*)&outXF[base + 4 * i] = xf;
            *(float4*)&xa[4 * i] = xn;
        }
        WAVE_SYNC();
    }
}

extern "C" void kernel_launch(void* const* d_in, const int* in_sizes, int n_in,
                              void* d_out, int out_size, void* d_ws, size_t ws_size,
                              hipStream_t stream) {
    const float* x   = (const float*)d_in[0];
    const float* c1w = (const float*)d_in[1];
    const float* c1b = (const float*)d_in[2];
    const float* c2w = (const float*)d_in[3];
    const float* c2b = (const float*)d_in[4];
    const float* l1w = (const float*)d_in[5];
    const float* l1b = (const float*)d_in[6];
    const float* l2w = (const float*)d_in[7];
    const float* l2b = (const float*)d_in[8];
    const float* l3w = (const float*)d_in[9];
    const float* l3b = (const float*)d_in[10];

    float* out = (float*)d_out;
    const size_t plane = (size_t)FBANKS * BATCH * D_IN;
    float* outH  = out;
    float* outXF = out + plane;
    float* outXS = out + 2 * plane;
    float* outF0 = out + 3 * plane;

    dim3 grid(BATCH / NW);
    dim3 block(256);
    fb_kernel<<<grid, block, 0, stream>>>(x, c1w, c1b, c2w, c2b,
                                          l1w, l1b, l2w, l2b, l3w, l3b,
                                          outH, outXF, outXS, outF0);
}